// Round 1
// baseline (80.748 us; speedup 1.0000x reference)
//
#include <hip/hip_runtime.h>

// GeometryRefiner: 3 Adam iterations on analytic gradient of
// bond + angle + clash + restraint loss. B=2, S=256, A=5.

#define S_ 256
#define A_ 5
#define NATOM 1280           // S_*A_
#define NB3 3840             // NATOM*3
#define NEL 7680             // B*NB3
#define SPLIT 8
#define ATOMS_PER_BLOCK 32   // 256/SPLIT
#define BLOCKS_PER_BATCH 40  // NATOM/ATOMS_PER_BLOCK

// 2*W/(normalizer) coefficients (d/dx of squared terms)
#define COEF_BOND2  (10.0f/1275.0f)       // 2*10/(2*1275)
#define COEF_ANGLE2 (10.0f/1536.0f)       // 2*5/(2*256*3)
#define COEF_CLASH2 (20.0f/1619250.0f)    // 2*20/(2*1619250)
#define COEF_REST2  (2.0f/32640.0f)       // 2*2/(2*32640)
#define TGT_ANG 1.91113553f               // 109.5 * pi / 180

__device__ __forceinline__ void angle_accum(const float* xs, int q, int role,
                                            float& gx, float& gy, float& gz) {
    // triple (q-1, q, q+1), all within one residue
    const float* P = xs + (q - 1) * 3;
    const float* Q = xs + q * 3;
    const float* R = xs + (q + 1) * 3;
    float v1x = P[0] - Q[0], v1y = P[1] - Q[1], v1z = P[2] - Q[2];
    float v2x = R[0] - Q[0], v2y = R[1] - Q[1], v2z = R[2] - Q[2];
    float n1 = sqrtf(v1x * v1x + v1y * v1y + v1z * v1z);
    float n2 = sqrtf(v2x * v2x + v2y * v2y + v2z * v2z);
    float n1m = fmaxf(n1, 1e-8f), n2m = fmaxf(n2, 1e-8f);
    float dot = v1x * v2x + v1y * v2y + v1z * v2z;
    float inv1 = 1.0f / n1m, inv2 = 1.0f / n2m;
    float inv12 = inv1 * inv2;
    float cosv = dot * inv12;
    float cc = fminf(fmaxf(cosv, -1.0f), 1.0f);
    float ang = acosf(cc);
    float G = 0.0f;
    if (cosv > -1.0f && cosv < 1.0f) {
        G = -COEF_ANGLE2 * (ang - TGT_ANG) * rsqrtf(1.0f - cosv * cosv);
    }
    float a1 = cosv * inv1 * inv1, a2 = cosv * inv2 * inv2;
    float d1x = inv12 * v2x - a1 * v1x;
    float d1y = inv12 * v2y - a1 * v1y;
    float d1z = inv12 * v2z - a1 * v1z;
    float d2x = inv12 * v1x - a2 * v2x;
    float d2y = inv12 * v1y - a2 * v2y;
    float d2z = inv12 * v1z - a2 * v2z;
    if (role == 0)      { gx += G * d1x; gy += G * d1y; gz += G * d1z; }
    else if (role == 2) { gx += G * d2x; gy += G * d2y; gz += G * d2z; }
    else                { gx -= G * (d1x + d2x); gy -= G * (d1y + d2y); gz -= G * (d1z + d2z); }
}

__global__ __launch_bounds__(256) void geo_grad(const float* __restrict__ x,
                                                const float* __restrict__ restr,
                                                float* __restrict__ grad) {
    __shared__ float xs[NB3];
    const int b = blockIdx.x / BLOCKS_PER_BATCH;
    const int base = (blockIdx.x % BLOCKS_PER_BATCH) * ATOMS_PER_BLOCK;
    const float* xb = x + b * NB3;
    for (int i = threadIdx.x; i < NB3 / 4; i += 256)
        ((float4*)xs)[i] = ((const float4*)xb)[i];
    __syncthreads();

    const int la = threadIdx.x >> 3;
    const int sub = threadIdx.x & 7;
    const int n = base + la;          // atom index in batch, 0..1279
    const int s = n / A_;             // residue
    const int a = n - s * A_;         // atom within residue
    const float xn0 = xs[n * 3], xn1 = xs[n * 3 + 1], xn2 = xs[n * 3 + 2];

    // ---- clash partial: sum over residues mr = sub, sub+8, ...
    float cgx = 0.f, cgy = 0.f, cgz = 0.f;
    for (int mr = sub; mr < S_; mr += SPLIT) {
        int dres = mr - s;
        if (dres >= -1 && dres <= 1) continue;   // pm excludes |res diff| <= 1
        const float* xm = xs + mr * 15;          // mr*A_*3
        #pragma unroll
        for (int ma = 0; ma < A_; ++ma) {
            float dx = xn0 - xm[ma * 3 + 0];
            float dy = xn1 - xm[ma * 3 + 1];
            float dz = xn2 - xm[ma * 3 + 2];
            float d2 = dx * dx + dy * dy + dz * dz;
            if (d2 > 1e-12f && d2 < 4.0f) {      // grad active iff d < CLASH_THRESH
                float inv = rsqrtf(d2);
                cgx += dx * inv; cgy += dy * inv; cgz += dz * inv;
            }
        }
    }

    // ---- restraint partial (rep atoms only, a == 0; rep index i = s)
    float rgx = 0.f, rgy = 0.f, rgz = 0.f;
    if (a == 0) {
        const int i = s;
        const float* rb = restr + b * (S_ * S_);
        for (int j = sub; j < S_; j += SPLIT) {
            if (j == i) continue;
            const float* xj = xs + j * 15;
            float dx = xn0 - xj[0], dy = xn1 - xj[1], dz = xn2 - xj[2];
            float d2 = dx * dx + dy * dy + dz * dz;
            if (d2 > 1e-12f) {
                float inv = rsqrtf(d2);
                float dr = d2 * inv;             // sqrt(d2)
                float rv = (i < j) ? rb[i * S_ + j] : rb[j * S_ + i];
                float w = (dr - rv) * inv;
                rgx += w * dx; rgy += w * dy; rgz += w * dz;
            }
        }
    }

    float tx = -COEF_CLASH2 * cgx + COEF_REST2 * rgx;
    float ty = -COEF_CLASH2 * cgy + COEF_REST2 * rgy;
    float tz = -COEF_CLASH2 * cgz + COEF_REST2 * rgz;
    #pragma unroll
    for (int m = 1; m < SPLIT; m <<= 1) {
        tx += __shfl_xor(tx, m);
        ty += __shfl_xor(ty, m);
        tz += __shfl_xor(tz, m);
    }

    if (sub == 0) {
        // ---- bonds: flat-consecutive pair (k, k+1) exists iff k <= 1274
        //      (covers intra a<4 and inter a==4->next residue; residue 255 intra excluded)
        if (n >= 1 && n <= 1275) {               // left bond (n-1, n)
            float dx = xn0 - xs[(n - 1) * 3];
            float dy = xn1 - xs[(n - 1) * 3 + 1];
            float dz = xn2 - xs[(n - 1) * 3 + 2];
            float d2 = dx * dx + dy * dy + dz * dz;
            float inv = rsqrtf(d2);
            float w = COEF_BOND2 * (1.0f - 1.5f * inv);   // (l-1.5)/l
            tx += w * dx; ty += w * dy; tz += w * dz;
        }
        if (n <= 1274) {                         // right bond (n, n+1)
            float dx = xn0 - xs[(n + 1) * 3];
            float dy = xn1 - xs[(n + 1) * 3 + 1];
            float dz = xn2 - xs[(n + 1) * 3 + 2];
            float d2 = dx * dx + dy * dy + dz * dz;
            float inv = rsqrtf(d2);
            float w = COEF_BOND2 * (1.0f - 1.5f * inv);
            tx += w * dx; ty += w * dy; tz += w * dz;
        }
        // ---- angles: roles within residue (centers at a = 1..3)
        if (a <= A_ - 3) angle_accum(xs, n + 1, 0, tx, ty, tz);           // left arm
        if (a >= 1 && a <= A_ - 2) angle_accum(xs, n, 1, tx, ty, tz);     // center
        if (a >= 2) angle_accum(xs, n - 1, 2, tx, ty, tz);                // right arm

        float* go = grad + b * NB3 + n * 3;
        go[0] = tx; go[1] = ty; go[2] = tz;
    }
}

__global__ __launch_bounds__(256) void geo_adam(const float* __restrict__ xin,
                                                const float* __restrict__ grad,
                                                float* __restrict__ m,
                                                float* __restrict__ v,
                                                float* __restrict__ xout,
                                                float bc1, float bc2, int t) {
    int i = blockIdx.x * blockDim.x + threadIdx.x;
    if (i >= NEL) return;
    float g = grad[i];
    float mp = (t == 1) ? 0.0f : m[i];
    float vp = (t == 1) ? 0.0f : v[i];
    float mn = 0.9f * mp + 0.1f * g;
    float vn = 0.999f * vp + 0.001f * g * g;
    m[i] = mn; v[i] = vn;
    float mh = mn / bc1;
    float vh = vn / bc2;
    xout[i] = xin[i] - 0.01f * mh / (sqrtf(vh) + 1e-8f);
}

extern "C" void kernel_launch(void* const* d_in, const int* in_sizes, int n_in,
                              void* d_out, int out_size, void* d_ws, size_t ws_size,
                              hipStream_t stream) {
    const float* coords = (const float*)d_in[0];
    const float* restr  = (const float*)d_in[1];
    // d_in[2] (mask) is unused by the reference.
    float* out = (float*)d_out;
    float* ws  = (float*)d_ws;
    float* xws = ws;              // NEL floats
    float* m   = ws + NEL;        // NEL floats
    float* v   = ws + 2 * NEL;    // NEL floats
    float* g   = ws + 3 * NEL;    // NEL floats

    const int GB = 2 * BLOCKS_PER_BATCH;   // 80 grad blocks
    const int UB = (NEL + 255) / 256;      // 30 update blocks

    // t = 1
    geo_grad<<<GB, 256, 0, stream>>>(coords, restr, g);
    geo_adam<<<UB, 256, 0, stream>>>(coords, g, m, v, xws, 0.1f, 0.001f, 1);
    // t = 2
    geo_grad<<<GB, 256, 0, stream>>>(xws, restr, g);
    geo_adam<<<UB, 256, 0, stream>>>(xws, g, m, v, xws, 0.19f, 0.001999f, 2);
    // t = 3
    geo_grad<<<GB, 256, 0, stream>>>(xws, restr, g);
    geo_adam<<<UB, 256, 0, stream>>>(xws, g, m, v, out, 0.271f, 0.002997001f, 3);
}

// Round 2
// 55.836 us; speedup vs baseline: 1.4462x; 1.4462x over previous
//
#include <hip/hip_runtime.h>

// GeometryRefiner: 3 Adam iterations on analytic gradient of
// bond + angle + clash + restraint loss. B=2, S=256, A=5.
// Fused: K1 = grad(x0) -> g1 ; K2 = adam1(redundant) + grad(x1) -> g2 ;
//        K3 = adam1+2(redundant) + grad(x2) + adam3 -> out.

#define S_ 256
#define A_ 5
#define NATOM 1280           // S_*A_
#define NB3 3840             // NATOM*3
#define NF4 960              // NB3/4
#define NEL 7680             // B*NB3
#define SPLIT 16
#define ATOMS_PER_BLOCK 16   // 256/SPLIT
#define BLOCKS_PER_BATCH 80  // NATOM/ATOMS_PER_BLOCK
#define GRID (2 * BLOCKS_PER_BATCH)

// 2*W/(normalizer) coefficients (d/dx of squared terms)
#define COEF_BOND2  (10.0f/1275.0f)
#define COEF_ANGLE2 (10.0f/1536.0f)
#define COEF_CLASH2 (20.0f/1619250.0f)
#define COEF_REST2  (2.0f/32640.0f)
#define TGT_ANG 1.91113553f               // 109.5 * pi / 180

__device__ __forceinline__ float adam_step1(float x, float g) {
    float mn = 0.1f * g;
    float vn = 0.001f * g * g;
    float mh = mn / 0.1f;
    float vh = vn / 0.001f;
    return x - 0.01f * mh / (sqrtf(vh) + 1e-8f);
}

__device__ __forceinline__ float adam_step2(float x, float g1, float g2) {
    float m1 = 0.1f * g1;
    float v1 = 0.001f * g1 * g1;
    float mh1 = m1 / 0.1f;
    float vh1 = v1 / 0.001f;
    float x1 = x - 0.01f * mh1 / (sqrtf(vh1) + 1e-8f);
    float m2 = 0.9f * m1 + 0.1f * g2;
    float v2 = 0.999f * v1 + 0.001f * g2 * g2;
    float mh2 = m2 / 0.19f;
    float vh2 = v2 / 0.001999f;
    return x1 - 0.01f * mh2 / (sqrtf(vh2) + 1e-8f);
}

__device__ __forceinline__ void angle_accum(const float* xs, int q, int role,
                                            float& gx, float& gy, float& gz) {
    const float* P = xs + (q - 1) * 3;
    const float* Q = xs + q * 3;
    const float* R = xs + (q + 1) * 3;
    float v1x = P[0] - Q[0], v1y = P[1] - Q[1], v1z = P[2] - Q[2];
    float v2x = R[0] - Q[0], v2y = R[1] - Q[1], v2z = R[2] - Q[2];
    float n1 = sqrtf(v1x * v1x + v1y * v1y + v1z * v1z);
    float n2 = sqrtf(v2x * v2x + v2y * v2y + v2z * v2z);
    float n1m = fmaxf(n1, 1e-8f), n2m = fmaxf(n2, 1e-8f);
    float dot = v1x * v2x + v1y * v2y + v1z * v2z;
    float inv1 = 1.0f / n1m, inv2 = 1.0f / n2m;
    float inv12 = inv1 * inv2;
    float cosv = dot * inv12;
    float cc = fminf(fmaxf(cosv, -1.0f), 1.0f);
    float ang = acosf(cc);
    float G = 0.0f;
    if (cosv > -1.0f && cosv < 1.0f) {
        G = -COEF_ANGLE2 * (ang - TGT_ANG) * rsqrtf(1.0f - cosv * cosv);
    }
    float a1 = cosv * inv1 * inv1, a2 = cosv * inv2 * inv2;
    float d1x = inv12 * v2x - a1 * v1x;
    float d1y = inv12 * v2y - a1 * v1y;
    float d1z = inv12 * v2z - a1 * v1z;
    float d2x = inv12 * v1x - a2 * v2x;
    float d2y = inv12 * v1y - a2 * v2y;
    float d2z = inv12 * v1z - a2 * v2z;
    if (role == 0)      { gx += G * d1x; gy += G * d1y; gz += G * d1z; }
    else if (role == 2) { gx += G * d2x; gy += G * d2y; gz += G * d2z; }
    else                { gx -= G * (d1x + d2x); gy -= G * (d1y + d2y); gz -= G * (d1z + d2z); }
}

// Full gradient for atom n; valid in (tx,ty,tz) at sub==0 after return.
__device__ __forceinline__ void grad_body(const float* xs, const float* rb,
                                          int n, int sub,
                                          float& tx, float& ty, float& tz) {
    const int s = n / A_;
    const int a = n - s * A_;
    const float xn0 = xs[n * 3], xn1 = xs[n * 3 + 1], xn2 = xs[n * 3 + 2];

    // clash partial over residues mr = sub, sub+16, ...
    float cgx = 0.f, cgy = 0.f, cgz = 0.f;
    for (int mr = sub; mr < S_; mr += SPLIT) {
        int dres = mr - s;
        if (dres >= -1 && dres <= 1) continue;
        const float* xm = xs + mr * 15;
        #pragma unroll
        for (int ma = 0; ma < A_; ++ma) {
            float dx = xn0 - xm[ma * 3 + 0];
            float dy = xn1 - xm[ma * 3 + 1];
            float dz = xn2 - xm[ma * 3 + 2];
            float d2 = dx * dx + dy * dy + dz * dz;
            if (d2 > 1e-12f && d2 < 4.0f) {
                float inv = rsqrtf(d2);
                cgx += dx * inv; cgy += dy * inv; cgz += dz * inv;
            }
        }
    }

    // restraint partial (rep atoms only, a == 0; rep index i = s)
    float rgx = 0.f, rgy = 0.f, rgz = 0.f;
    if (a == 0) {
        const int i = s;
        for (int j = sub; j < S_; j += SPLIT) {
            if (j == i) continue;
            const float* xj = xs + j * 15;
            float dx = xn0 - xj[0], dy = xn1 - xj[1], dz = xn2 - xj[2];
            float d2 = dx * dx + dy * dy + dz * dz;
            if (d2 > 1e-12f) {
                float inv = rsqrtf(d2);
                float dr = d2 * inv;
                float rv = (i < j) ? rb[i * S_ + j] : rb[j * S_ + i];
                float w = (dr - rv) * inv;
                rgx += w * dx; rgy += w * dy; rgz += w * dz;
            }
        }
    }

    tx = -COEF_CLASH2 * cgx + COEF_REST2 * rgx;
    ty = -COEF_CLASH2 * cgy + COEF_REST2 * rgy;
    tz = -COEF_CLASH2 * cgz + COEF_REST2 * rgz;
    #pragma unroll
    for (int m = 1; m < SPLIT; m <<= 1) {
        tx += __shfl_xor(tx, m);
        ty += __shfl_xor(ty, m);
        tz += __shfl_xor(tz, m);
    }

    if (sub == 0) {
        if (n >= 1 && n <= 1275) {               // left bond (n-1, n)
            float dx = xn0 - xs[(n - 1) * 3];
            float dy = xn1 - xs[(n - 1) * 3 + 1];
            float dz = xn2 - xs[(n - 1) * 3 + 2];
            float d2 = dx * dx + dy * dy + dz * dz;
            float inv = rsqrtf(d2);
            float w = COEF_BOND2 * (1.0f - 1.5f * inv);
            tx += w * dx; ty += w * dy; tz += w * dz;
        }
        if (n <= 1274) {                         // right bond (n, n+1)
            float dx = xn0 - xs[(n + 1) * 3];
            float dy = xn1 - xs[(n + 1) * 3 + 1];
            float dz = xn2 - xs[(n + 1) * 3 + 2];
            float d2 = dx * dx + dy * dy + dz * dz;
            float inv = rsqrtf(d2);
            float w = COEF_BOND2 * (1.0f - 1.5f * inv);
            tx += w * dx; ty += w * dy; tz += w * dz;
        }
        if (a <= A_ - 3) angle_accum(xs, n + 1, 0, tx, ty, tz);
        if (a >= 1 && a <= A_ - 2) angle_accum(xs, n, 1, tx, ty, tz);
        if (a >= 2) angle_accum(xs, n - 1, 2, tx, ty, tz);
    }
}

// K1: grad(x0) -> g1
__global__ __launch_bounds__(256) void k_grad1(const float* __restrict__ x0,
                                               const float* __restrict__ restr,
                                               float* __restrict__ g1) {
    __shared__ float xs[NB3];
    const int b = blockIdx.x / BLOCKS_PER_BATCH;
    const int base = (blockIdx.x % BLOCKS_PER_BATCH) * ATOMS_PER_BLOCK;
    const float* xb = x0 + b * NB3;
    for (int i = threadIdx.x; i < NF4; i += 256)
        ((float4*)xs)[i] = ((const float4*)xb)[i];
    __syncthreads();

    const int la = threadIdx.x >> 4;
    const int sub = threadIdx.x & (SPLIT - 1);
    const int n = base + la;
    float tx, ty, tz;
    grad_body(xs, restr + b * (S_ * S_), n, sub, tx, ty, tz);
    if (sub == 0) {
        float* go = g1 + b * NB3 + n * 3;
        go[0] = tx; go[1] = ty; go[2] = tz;
    }
}

// K2: x1 = adam1(x0,g1) staged redundantly; grad(x1) -> g2
__global__ __launch_bounds__(256) void k_grad2(const float* __restrict__ x0,
                                               const float* __restrict__ restr,
                                               const float* __restrict__ g1,
                                               float* __restrict__ g2) {
    __shared__ float xs[NB3];
    const int b = blockIdx.x / BLOCKS_PER_BATCH;
    const int base = (blockIdx.x % BLOCKS_PER_BATCH) * ATOMS_PER_BLOCK;
    const float* xb = x0 + b * NB3;
    const float* gb = g1 + b * NB3;
    for (int i = threadIdx.x; i < NF4; i += 256) {
        float4 xv = ((const float4*)xb)[i];
        float4 gv = ((const float4*)gb)[i];
        float4 o;
        o.x = adam_step1(xv.x, gv.x);
        o.y = adam_step1(xv.y, gv.y);
        o.z = adam_step1(xv.z, gv.z);
        o.w = adam_step1(xv.w, gv.w);
        ((float4*)xs)[i] = o;
    }
    __syncthreads();

    const int la = threadIdx.x >> 4;
    const int sub = threadIdx.x & (SPLIT - 1);
    const int n = base + la;
    float tx, ty, tz;
    grad_body(xs, restr + b * (S_ * S_), n, sub, tx, ty, tz);
    if (sub == 0) {
        float* go = g2 + b * NB3 + n * 3;
        go[0] = tx; go[1] = ty; go[2] = tz;
    }
}

// K3: x2 = adam2(x0,g1,g2) staged redundantly; g3 = grad(x2); out = adam3.
__global__ __launch_bounds__(256) void k_grad3(const float* __restrict__ x0,
                                               const float* __restrict__ restr,
                                               const float* __restrict__ g1,
                                               const float* __restrict__ g2,
                                               float* __restrict__ out) {
    __shared__ float xs[NB3];
    const int b = blockIdx.x / BLOCKS_PER_BATCH;
    const int base = (blockIdx.x % BLOCKS_PER_BATCH) * ATOMS_PER_BLOCK;
    const float* xb  = x0 + b * NB3;
    const float* g1b = g1 + b * NB3;
    const float* g2b = g2 + b * NB3;
    for (int i = threadIdx.x; i < NF4; i += 256) {
        float4 xv = ((const float4*)xb)[i];
        float4 a1 = ((const float4*)g1b)[i];
        float4 a2 = ((const float4*)g2b)[i];
        float4 o;
        o.x = adam_step2(xv.x, a1.x, a2.x);
        o.y = adam_step2(xv.y, a1.y, a2.y);
        o.z = adam_step2(xv.z, a1.z, a2.z);
        o.w = adam_step2(xv.w, a1.w, a2.w);
        ((float4*)xs)[i] = o;
    }
    __syncthreads();

    const int la = threadIdx.x >> 4;
    const int sub = threadIdx.x & (SPLIT - 1);
    const int n = base + la;
    float tx, ty, tz;
    grad_body(xs, restr + b * (S_ * S_), n, sub, tx, ty, tz);
    if (sub == 0) {
        const float* g1p = g1b + n * 3;
        const float* g2p = g2b + n * 3;
        float g3[3] = {tx, ty, tz};
        float* go = out + b * NB3 + n * 3;
        #pragma unroll
        for (int c = 0; c < 3; ++c) {
            float G1 = g1p[c], G2 = g2p[c], G3 = g3[c];
            float m1 = 0.1f * G1;
            float v1 = 0.001f * G1 * G1;
            float m2 = 0.9f * m1 + 0.1f * G2;
            float v2 = 0.999f * v1 + 0.001f * G2 * G2;
            float m3 = 0.9f * m2 + 0.1f * G3;
            float v3 = 0.999f * v2 + 0.001f * G3 * G3;
            float mh = m3 / 0.271f;
            float vh = v3 / 0.002997001f;
            go[c] = xs[n * 3 + c] - 0.01f * mh / (sqrtf(vh) + 1e-8f);
        }
    }
}

extern "C" void kernel_launch(void* const* d_in, const int* in_sizes, int n_in,
                              void* d_out, int out_size, void* d_ws, size_t ws_size,
                              hipStream_t stream) {
    const float* coords = (const float*)d_in[0];
    const float* restr  = (const float*)d_in[1];
    float* out = (float*)d_out;
    float* ws  = (float*)d_ws;
    float* g1  = ws;              // NEL floats
    float* g2  = ws + NEL;        // NEL floats

    k_grad1<<<GRID, 256, 0, stream>>>(coords, restr, g1);
    k_grad2<<<GRID, 256, 0, stream>>>(coords, restr, g1, g2);
    k_grad3<<<GRID, 256, 0, stream>>>(coords, restr, g1, g2, out);
}